// Round 8
// baseline (142.541 us; speedup 1.0000x reference)
//
#include <hip/hip_runtime.h>
#include <hip/hip_bf16.h>
#include <math.h>

// NTXent loss, N=8192 rows, D=128.
// loss = mean_i [ log(sum_{j!=i} exp(2*cos_ij)) - 2*cos_{i,partner} ]
// R16 == R15 resubmit (container infra failure, no data). Theory unchanged:
// sim's ~36us stall survived occupancy (R14) and barrier-schedule (R13)
// changes => the triangle/colsum machinery is the suspect. Trade 2x MFMA
// (+2us issue, 3%-utilized pipe) for a radically simple dataflow: FULL
// matrix, row-sums only. 1024 identical blocks (64 row-strips x 16
// col-groups of 512 cols) = one clean 4/CU generation; B streams as 16
// chunks of 32 cols through a 4-slot rolling LDS buffer with counted vmcnt
// (depth-3 prefetch, never 0 until tail); no colsum, no triangle decode,
// no setprio. part = 16 slots. vmcnt ledger re-audited: prologue 8 A-loads
// + 8 glds; phase0 vmcnt(6) drains A+chunk0; steady 8->6; tail 4/2/0.

typedef __attribute__((ext_vector_type(8))) short bf16x8;   // 8 bf16 = 4 VGPRs
typedef __attribute__((ext_vector_type(4))) float f32x4;

#define NROWS 8192
#define DDIM  128
#define BHALF 4096
#define CHUNK 32
#define TILE  128
#define NCG   16                    // col groups per row
#define CGSZ  512                   // cols per group
#define NCHUNK 16                   // 16 chunks of 32 cols per block
// zn scaled by sqrt(2/ln2): acc = (2/ln2)*cos, exp(2cos) = exp2(acc)
#define SQRT_E2S 1.6986435980707531f
#define LN2      0.6931471805599453f
#define EXPDIAG  7.38905609893065f

static __device__ __forceinline__ unsigned short f2bf(float f) {
  unsigned int u = __float_as_uint(f);
  unsigned int r = (u + 0x7fffu + ((u >> 16) & 1u)) >> 16;   // RNE
  return (unsigned short)r;
}

static __device__ __forceinline__ void glds16(const unsigned short* g, unsigned short* l) {
  __builtin_amdgcn_global_load_lds((const __attribute__((address_space(1))) unsigned int*)g,
                                   (__attribute__((address_space(3))) unsigned int*)l,
                                   16, 0, 0);
}

// ---- Kernel 1: normalize (scaled) + fp32 pair-dots + zero out ------------
// Block b: waves 0,1 -> rows 2b,2b+1 (zi); waves 2,3 -> their partners (zj).
__global__ void norm_kernel(const float* __restrict__ zi, const float* __restrict__ zj,
                            unsigned short* __restrict__ zn,
                            float* __restrict__ pos, float* __restrict__ out) {
  __shared__ float2 xbuf[2][64];
  int wave = threadIdx.x >> 6;
  int lane = threadIdx.x & 63;
  int pi   = blockIdx.x * 2 + (wave & 1);           // pair index
  int row  = pi + (wave >> 1) * BHALF;
  const float* src = (row < BHALF) ? (zi + (size_t)row * DDIM)
                                   : (zj + (size_t)(row - BHALF) * DDIM);
  float2 v = *(const float2*)(src + 2 * lane);
  float ss = v.x * v.x + v.y * v.y;
  #pragma unroll
  for (int off = 1; off < 64; off <<= 1) ss += __shfl_xor(ss, off);
  float scale = SQRT_E2S / fmaxf(sqrtf(ss), 1e-8f);
  v.x *= scale; v.y *= scale;
  unsigned int lo = f2bf(v.x), hi = f2bf(v.y);
  ((unsigned int*)(zn + (size_t)row * DDIM))[lane] = lo | (hi << 16);

  if (wave >= 2) xbuf[wave - 2][lane] = v;
  __syncthreads();
  if (wave < 2) {                                    // d = (2/ln2)*cos(i, i+B)
    float2 w = xbuf[wave][lane];
    float d = v.x * w.x + v.y * w.y;
    #pragma unroll
    for (int off = 1; off < 64; off <<= 1) d += __shfl_xor(d, off);
    if (lane == 0) pos[pi] = d;
  }
  if (blockIdx.x == 0 && threadIdx.x == 0) out[0] = 0.0f;
}

// ---- Kernel 2: full-matrix sim + exp + row partial sums ------------------
// 1024 blocks: strip = bid>>4 (128 rows), cg = bid&15 (512 cols).
// A-panel in regs; B streamed as 16 chunks of 32 cols through a 4-slot
// rolling LDS buffer (counted vmcnt, depth-3 prefetch). Row sums only.
__global__ __launch_bounds__(256, 4)
void sim_kernel(const unsigned short* __restrict__ zn, float* __restrict__ part) {
  __shared__ unsigned short lds[4 * CHUNK * DDIM];   // 4 slots x 8 KB

  const int strip = blockIdx.x >> 4;
  const int cg    = blockIdx.x & 15;
  const int wave  = threadIdx.x >> 6;
  const int lane  = threadIdx.x & 63;
  const int l15   = lane & 15;
  const int quad  = lane >> 4;

  const int row_base = strip * TILE + wave * 32;
  const int col0     = cg * CGSZ;

  // A fragments: A[m=l15][k=quad*8+j], 2 mi-tiles x 4 k-frags = 32 VGPRs.
  // Issued FIRST (oldest in vmcnt order), pinned by sched_barrier below.
  bf16x8 a[2][4];
  const unsigned short* abase = zn + (size_t)(row_base + l15) * DDIM + quad * 8;
  #pragma unroll
  for (int mi = 0; mi < 2; ++mi)
    #pragma unroll
    for (int kf = 0; kf < 4; ++kf)
      a[mi][kf] = *(const bf16x8*)(abase + mi * 16 * DDIM + kf * 32);
  __builtin_amdgcn_sched_barrier(0);   // pin: A-loads strictly before glds

  // Staging: chunk buffer = 32 B-rows x 16 slots of 16B; slot t2 -> row
  // t2>>4, col-chunk (t2&15)^(row&15) [XOR swizzle]. 2 issues/chunk/thread.
  const int t0 = wave * 64 + lane;
  const int r0 = t0 >> 4,         c0 = (t0 & 15) ^ (r0 & 15);
  const int r1 = (t0 + 256) >> 4, c1 = (t0 & 15) ^ (r1 & 15);
  const unsigned short* gst0 = zn + (size_t)(col0 + r0) * DDIM + c0 * 8;
  const unsigned short* gst1 = zn + (size_t)(col0 + r1) * DDIM + c1 * 8;

  #pragma unroll
  for (int ch = 0; ch < 4; ++ch) {                   // prime chunks 0..3
    glds16(gst0 + (size_t)ch * CHUNK * DDIM, lds + ch * 4096 + wave * 512);
    glds16(gst1 + (size_t)ch * CHUNK * DDIM, lds + ch * 4096 + 2048 + wave * 512);
  }
  __builtin_amdgcn_sched_barrier(0);   // pin: glds issued before loop body

  int rdoff[4];
  #pragma unroll
  for (int kf = 0; kf < 4; ++kf)
    rdoff[kf] = l15 * DDIM + (((quad + 4 * kf) ^ l15) << 3);

  float rs[2][4];
  #pragma unroll
  for (int mi = 0; mi < 2; ++mi)
    #pragma unroll
    for (int r = 0; r < 4; ++r) rs[mi][r] = 0.0f;

// Phase CH: wait own chunk-CH staging (VM = 2 x chunks-still-in-flight) ->
// barrier (all waves' chunk CH in LDS) -> compute -> barrier (slot reads
// done block-wide) -> issue chunk CH+4 into the freed slot.
#define SIM_PHASE(CH, VM)                                                      \
  {                                                                            \
    asm volatile("s_waitcnt vmcnt(" VM ")" ::: "memory");                      \
    __builtin_amdgcn_s_barrier();                                              \
    __builtin_amdgcn_sched_barrier(0);                                         \
    const unsigned short* lb = lds + ((CH) & 3) * 4096;                        \
    _Pragma("unroll")                                                          \
    for (int ni = 0; ni < 2; ++ni) {                                           \
      bf16x8 b[4];                                                             \
      _Pragma("unroll")                                                        \
      for (int kf = 0; kf < 4; ++kf)                                           \
        b[kf] = *(const bf16x8*)(lb + ni * 16 * DDIM + rdoff[kf]);             \
      f32x4 acc[2];                                                            \
      _Pragma("unroll")                                                        \
      for (int mi = 0; mi < 2; ++mi) {                                         \
        f32x4 z = {0.0f, 0.0f, 0.0f, 0.0f};                                    \
        acc[mi] = __builtin_amdgcn_mfma_f32_16x16x32_bf16(a[mi][0], b[0], z, 0, 0, 0); \
      }                                                                        \
      _Pragma("unroll")                                                        \
      for (int kf = 1; kf < 4; ++kf)                                           \
        _Pragma("unroll")                                                      \
        for (int mi = 0; mi < 2; ++mi)                                         \
          acc[mi] = __builtin_amdgcn_mfma_f32_16x16x32_bf16(a[mi][kf], b[kf], acc[mi], 0, 0, 0); \
      _Pragma("unroll")                                                        \
      for (int mi = 0; mi < 2; ++mi)                                           \
        _Pragma("unroll")                                                      \
        for (int r = 0; r < 4; ++r)                                            \
          rs[mi][r] += __builtin_amdgcn_exp2f(acc[mi][r]);                     \
    }                                                                          \
    __builtin_amdgcn_sched_barrier(0);                                         \
    __builtin_amdgcn_s_barrier();                                              \
    if ((CH) + 4 < NCHUNK) {                                                   \
      glds16(gst0 + (size_t)((CH) + 4) * CHUNK * DDIM,                         \
             lds + ((CH) & 3) * 4096 + wave * 512);                            \
      glds16(gst1 + (size_t)((CH) + 4) * CHUNK * DDIM,                         \
             lds + ((CH) & 3) * 4096 + 2048 + wave * 512);                     \
    }                                                                          \
  }

  SIM_PHASE(0,  "6")  SIM_PHASE(1,  "6")  SIM_PHASE(2,  "6")  SIM_PHASE(3,  "6")
  SIM_PHASE(4,  "6")  SIM_PHASE(5,  "6")  SIM_PHASE(6,  "6")  SIM_PHASE(7,  "6")
  SIM_PHASE(8,  "6")  SIM_PHASE(9,  "6")  SIM_PHASE(10, "6")  SIM_PHASE(11, "6")
  SIM_PHASE(12, "6")  SIM_PHASE(13, "4")  SIM_PHASE(14, "2")  SIM_PHASE(15, "0")
#undef SIM_PHASE

  // Row reduce across the 16 cols each l15 covers. C/D layout: col=l15,
  // row=quad*4+reg. Plain store to disjoint slot cg.
  #pragma unroll
  for (int mi = 0; mi < 2; ++mi)
    #pragma unroll
    for (int r = 0; r < 4; ++r) {
      float v = rs[mi][r];
      v += __shfl_xor(v, 1);
      v += __shfl_xor(v, 2);
      v += __shfl_xor(v, 4);
      v += __shfl_xor(v, 8);
      if (l15 == 0)
        part[(size_t)cg * NROWS + row_base + mi * 16 + quad * 4 + r] = v;
    }
}

// ---- Kernel 3: sum 16 slots per row, logs + mean -------------------------
__global__ void finalize_kernel(const float* __restrict__ part,
                                const float* __restrict__ pos,
                                float* __restrict__ out) {
  __shared__ float red[4];
  int r = blockIdx.x * 256 + threadIdx.x;            // grid 32 x 256 = 8192 rows
  float s = 0.0f;
  #pragma unroll
  for (int k = 0; k < NCG; ++k) s += part[(size_t)k * NROWS + r];
  // per row: logsumexp(logits) - logits[0] = log(S - e^2) - ln2 * pos
  float v = logf(s - EXPDIAG) - LN2 * pos[r & (BHALF - 1)];
  #pragma unroll
  for (int off = 1; off < 64; off <<= 1) v += __shfl_xor(v, off);
  int wave = threadIdx.x >> 6, lane = threadIdx.x & 63;
  if (lane == 0) red[wave] = v;
  __syncthreads();
  if (threadIdx.x == 0)
    atomicAdd(out, (red[0] + red[1] + red[2] + red[3]) * (1.0f / 8192.0f));
}

extern "C" void kernel_launch(void* const* d_in, const int* in_sizes, int n_in,
                              void* d_out, int out_size, void* d_ws, size_t ws_size,
                              hipStream_t stream) {
  const float* zi = (const float*)d_in[0];
  const float* zj = (const float*)d_in[1];
  char* ws = (char*)d_ws;
  unsigned short* zn = (unsigned short*)ws;                       // 2 MB
  float* part = (float*)(ws + (size_t)NROWS * DDIM * 2);          // 512 KB (16x8192)
  float* pos  = (float*)(ws + (size_t)NROWS * DDIM * 2
                            + (size_t)NCG * NROWS * 4);           // 16 KB
  float* out = (float*)d_out;

  norm_kernel<<<2048, 256, 0, stream>>>(zi, zj, zn, pos, out);
  sim_kernel<<<1024, 256, 0, stream>>>(zn, part);
  finalize_kernel<<<32, 256, 0, stream>>>(part, pos, out);
}

// Round 9
// 92.290 us; speedup vs baseline: 1.5445x; 1.5445x over previous
//
#include <hip/hip_runtime.h>
#include <hip/hip_bf16.h>
#include <math.h>

// NTXent loss, N=8192 rows, D=128.
// loss = mean_i [ log(sum_{j!=i} exp(2*cos_ij)) - 2*cos_{i,partner} ]
// R17: R16's full-matrix rewrite was correct but the allocator spilled AGAIN
// (VGPR 64 = cap/2, 350 MB scratch = the whole 94us). Empirical rule after
// 4 data points: any launch_bounds VGPR cap <= 168 collapses to cap/2 +
// scratch; only (256,2)/cap-256 builds clean (R11: VGPR 128, no spill).
// launch_bounds is an allocator floor, not a residency cap: a 128-VGPR
// binary still co-schedules 4 blocks/CU. Changes vs R16: (1) (256,2);
// (2) roll the 13 steady-state phases into a loop (tail 13/14/15 explicit)
// to cut RA pressure from 16 unrolled bodies between sched_barrier walls.

typedef __attribute__((ext_vector_type(8))) short bf16x8;   // 8 bf16 = 4 VGPRs
typedef __attribute__((ext_vector_type(4))) float f32x4;

#define NROWS 8192
#define DDIM  128
#define BHALF 4096
#define CHUNK 32
#define TILE  128
#define NCG   16                    // col groups per row
#define CGSZ  512                   // cols per group
#define NCHUNK 16                   // 16 chunks of 32 cols per block
// zn scaled by sqrt(2/ln2): acc = (2/ln2)*cos, exp(2cos) = exp2(acc)
#define SQRT_E2S 1.6986435980707531f
#define LN2      0.6931471805599453f
#define EXPDIAG  7.38905609893065f

static __device__ __forceinline__ unsigned short f2bf(float f) {
  unsigned int u = __float_as_uint(f);
  unsigned int r = (u + 0x7fffu + ((u >> 16) & 1u)) >> 16;   // RNE
  return (unsigned short)r;
}

static __device__ __forceinline__ void glds16(const unsigned short* g, unsigned short* l) {
  __builtin_amdgcn_global_load_lds((const __attribute__((address_space(1))) unsigned int*)g,
                                   (__attribute__((address_space(3))) unsigned int*)l,
                                   16, 0, 0);
}

// ---- Kernel 1: normalize (scaled) + fp32 pair-dots + zero out ------------
// Block b: waves 0,1 -> rows 2b,2b+1 (zi); waves 2,3 -> their partners (zj).
__global__ void norm_kernel(const float* __restrict__ zi, const float* __restrict__ zj,
                            unsigned short* __restrict__ zn,
                            float* __restrict__ pos, float* __restrict__ out) {
  __shared__ float2 xbuf[2][64];
  int wave = threadIdx.x >> 6;
  int lane = threadIdx.x & 63;
  int pi   = blockIdx.x * 2 + (wave & 1);           // pair index
  int row  = pi + (wave >> 1) * BHALF;
  const float* src = (row < BHALF) ? (zi + (size_t)row * DDIM)
                                   : (zj + (size_t)(row - BHALF) * DDIM);
  float2 v = *(const float2*)(src + 2 * lane);
  float ss = v.x * v.x + v.y * v.y;
  #pragma unroll
  for (int off = 1; off < 64; off <<= 1) ss += __shfl_xor(ss, off);
  float scale = SQRT_E2S / fmaxf(sqrtf(ss), 1e-8f);
  v.x *= scale; v.y *= scale;
  unsigned int lo = f2bf(v.x), hi = f2bf(v.y);
  ((unsigned int*)(zn + (size_t)row * DDIM))[lane] = lo | (hi << 16);

  if (wave >= 2) xbuf[wave - 2][lane] = v;
  __syncthreads();
  if (wave < 2) {                                    // d = (2/ln2)*cos(i, i+B)
    float2 w = xbuf[wave][lane];
    float d = v.x * w.x + v.y * w.y;
    #pragma unroll
    for (int off = 1; off < 64; off <<= 1) d += __shfl_xor(d, off);
    if (lane == 0) pos[pi] = d;
  }
  if (blockIdx.x == 0 && threadIdx.x == 0) out[0] = 0.0f;
}

// ---- Kernel 2: full-matrix sim + exp + row partial sums ------------------
// 1024 blocks: strip = bid>>4 (128 rows), cg = bid&15 (512 cols).
// A-panel in regs; B streamed as 16 chunks of 32 cols through a 4-slot
// rolling LDS buffer (counted vmcnt, depth-3 prefetch). Row sums only.
__global__ __launch_bounds__(256, 2)
void sim_kernel(const unsigned short* __restrict__ zn, float* __restrict__ part) {
  __shared__ unsigned short lds[4 * CHUNK * DDIM];   // 4 slots x 8 KB

  const int strip = blockIdx.x >> 4;
  const int cg    = blockIdx.x & 15;
  const int wave  = threadIdx.x >> 6;
  const int lane  = threadIdx.x & 63;
  const int l15   = lane & 15;
  const int quad  = lane >> 4;

  const int row_base = strip * TILE + wave * 32;
  const int col0     = cg * CGSZ;

  // A fragments: A[m=l15][k=quad*8+j], 2 mi-tiles x 4 k-frags = 32 VGPRs.
  // Issued FIRST (oldest in vmcnt order), pinned by sched_barrier below.
  bf16x8 a[2][4];
  const unsigned short* abase = zn + (size_t)(row_base + l15) * DDIM + quad * 8;
  #pragma unroll
  for (int mi = 0; mi < 2; ++mi)
    #pragma unroll
    for (int kf = 0; kf < 4; ++kf)
      a[mi][kf] = *(const bf16x8*)(abase + mi * 16 * DDIM + kf * 32);
  __builtin_amdgcn_sched_barrier(0);   // pin: A-loads strictly before glds

  // Staging: chunk buffer = 32 B-rows x 16 slots of 16B; slot t2 -> row
  // t2>>4, col-chunk (t2&15)^(row&15) [XOR swizzle]. 2 issues/chunk/thread.
  const int t0 = wave * 64 + lane;
  const int r0 = t0 >> 4,         c0 = (t0 & 15) ^ (r0 & 15);
  const int r1 = (t0 + 256) >> 4, c1 = (t0 & 15) ^ (r1 & 15);
  const unsigned short* gst0 = zn + (size_t)(col0 + r0) * DDIM + c0 * 8;
  const unsigned short* gst1 = zn + (size_t)(col0 + r1) * DDIM + c1 * 8;

  #pragma unroll
  for (int ch = 0; ch < 4; ++ch) {                   // prime chunks 0..3
    glds16(gst0 + (size_t)ch * CHUNK * DDIM, lds + ch * 4096 + wave * 512);
    glds16(gst1 + (size_t)ch * CHUNK * DDIM, lds + ch * 4096 + 2048 + wave * 512);
  }
  __builtin_amdgcn_sched_barrier(0);   // pin: glds issued before loop body

  int rdoff[4];
  #pragma unroll
  for (int kf = 0; kf < 4; ++kf)
    rdoff[kf] = l15 * DDIM + (((quad + 4 * kf) ^ l15) << 3);

  float rs[2][4];
  #pragma unroll
  for (int mi = 0; mi < 2; ++mi)
    #pragma unroll
    for (int r = 0; r < 4; ++r) rs[mi][r] = 0.0f;

// Phase CH: wait own chunk-CH staging (VM = 2 x chunks-still-in-flight) ->
// barrier (all waves' chunk CH in LDS) -> compute -> barrier (slot reads
// done block-wide) -> issue chunk CH+4 into the freed slot (if any).
#define SIM_PHASE(CH, VM)                                                      \
  {                                                                            \
    asm volatile("s_waitcnt vmcnt(" VM ")" ::: "memory");                      \
    __builtin_amdgcn_s_barrier();                                              \
    __builtin_amdgcn_sched_barrier(0);                                         \
    const unsigned short* lb = lds + ((CH) & 3) * 4096;                        \
    _Pragma("unroll")                                                          \
    for (int ni = 0; ni < 2; ++ni) {                                           \
      bf16x8 b[4];                                                             \
      _Pragma("unroll")                                                        \
      for (int kf = 0; kf < 4; ++kf)                                           \
        b[kf] = *(const bf16x8*)(lb + ni * 16 * DDIM + rdoff[kf]);             \
      f32x4 acc[2];                                                            \
      _Pragma("unroll")                                                        \
      for (int mi = 0; mi < 2; ++mi) {                                         \
        f32x4 z = {0.0f, 0.0f, 0.0f, 0.0f};                                    \
        acc[mi] = __builtin_amdgcn_mfma_f32_16x16x32_bf16(a[mi][0], b[0], z, 0, 0, 0); \
      }                                                                        \
      _Pragma("unroll")                                                        \
      for (int kf = 1; kf < 4; ++kf)                                           \
        _Pragma("unroll")                                                      \
        for (int mi = 0; mi < 2; ++mi)                                         \
          acc[mi] = __builtin_amdgcn_mfma_f32_16x16x32_bf16(a[mi][kf], b[kf], acc[mi], 0, 0, 0); \
      _Pragma("unroll")                                                        \
      for (int mi = 0; mi < 2; ++mi)                                           \
        _Pragma("unroll")                                                      \
        for (int r = 0; r < 4; ++r)                                            \
          rs[mi][r] += __builtin_amdgcn_exp2f(acc[mi][r]);                     \
    }                                                                          \
    __builtin_amdgcn_sched_barrier(0);                                         \
    __builtin_amdgcn_s_barrier();                                              \
    if ((CH) + 4 < NCHUNK) {                                                   \
      glds16(gst0 + (size_t)((CH) + 4) * CHUNK * DDIM,                         \
             lds + ((CH) & 3) * 4096 + wave * 512);                            \
      glds16(gst1 + (size_t)((CH) + 4) * CHUNK * DDIM,                         \
             lds + ((CH) & 3) * 4096 + 2048 + wave * 512);                     \
    }                                                                          \
  }

  // Steady state rolled (13 iters, vmcnt(6)); tail explicit (4/2/0).
  for (int ch = 0; ch < 13; ++ch)
    SIM_PHASE(ch, "6")
  SIM_PHASE(13, "4")
  SIM_PHASE(14, "2")
  SIM_PHASE(15, "0")
#undef SIM_PHASE

  // Row reduce across the 16 cols each l15 covers. C/D layout: col=l15,
  // row=quad*4+reg. Plain store to disjoint slot cg.
  #pragma unroll
  for (int mi = 0; mi < 2; ++mi)
    #pragma unroll
    for (int r = 0; r < 4; ++r) {
      float v = rs[mi][r];
      v += __shfl_xor(v, 1);
      v += __shfl_xor(v, 2);
      v += __shfl_xor(v, 4);
      v += __shfl_xor(v, 8);
      if (l15 == 0)
        part[(size_t)cg * NROWS + row_base + mi * 16 + quad * 4 + r] = v;
    }
}

// ---- Kernel 3: sum 16 slots per row, logs + mean -------------------------
__global__ void finalize_kernel(const float* __restrict__ part,
                                const float* __restrict__ pos,
                                float* __restrict__ out) {
  __shared__ float red[4];
  int r = blockIdx.x * 256 + threadIdx.x;            // grid 32 x 256 = 8192 rows
  float s = 0.0f;
  #pragma unroll
  for (int k = 0; k < NCG; ++k) s += part[(size_t)k * NROWS + r];
  // per row: logsumexp(logits) - logits[0] = log(S - e^2) - ln2 * pos
  float v = logf(s - EXPDIAG) - LN2 * pos[r & (BHALF - 1)];
  #pragma unroll
  for (int off = 1; off < 64; off <<= 1) v += __shfl_xor(v, off);
  int wave = threadIdx.x >> 6, lane = threadIdx.x & 63;
  if (lane == 0) red[wave] = v;
  __syncthreads();
  if (threadIdx.x == 0)
    atomicAdd(out, (red[0] + red[1] + red[2] + red[3]) * (1.0f / 8192.0f));
}

extern "C" void kernel_launch(void* const* d_in, const int* in_sizes, int n_in,
                              void* d_out, int out_size, void* d_ws, size_t ws_size,
                              hipStream_t stream) {
  const float* zi = (const float*)d_in[0];
  const float* zj = (const float*)d_in[1];
  char* ws = (char*)d_ws;
  unsigned short* zn = (unsigned short*)ws;                       // 2 MB
  float* part = (float*)(ws + (size_t)NROWS * DDIM * 2);          // 512 KB (16x8192)
  float* pos  = (float*)(ws + (size_t)NROWS * DDIM * 2
                            + (size_t)NCG * NROWS * 4);           // 16 KB
  float* out = (float*)d_out;

  norm_kernel<<<2048, 256, 0, stream>>>(zi, zj, zn, pos, out);
  sim_kernel<<<1024, 256, 0, stream>>>(zn, part);
  finalize_kernel<<<32, 256, 0, stream>>>(part, pos, out);
}